// Round 9
// baseline (13.318 us; speedup 1.0000x reference)
//
#include <hip/hip_runtime.h>
#include <math.h>

#define IPB 2     // images per block
#define BLK 448   // 7 waves: covers 392 patch threads + 400 phase-E threads

__device__ __forceinline__ float2 pkfma(float2 a, float b, float2 c) {
    return make_float2(fmaf(a.x, b, c.x), fmaf(a.y, b, c.y));
}

// Fully fused, one launch. 448-thread blocks, 2 images/block (thread=(img,patch)).
// Patch-side sincos + pair products hoisted BEFORE prep so their latency hides
// under the prep barriers. Prep = 256-thread shfl-butterfly U build -> A -> C.
__global__ __launch_bounds__(BLK) void quanv_fused5_kernel(
    const float* __restrict__ x,       // [B,784]
    const float* __restrict__ params,  // [3,4,3]
    const float* __restrict__ Wm,      // [10,784]
    const float* __restrict__ bv,      // [10]
    float* __restrict__ out,           // [B,10]
    int B)
{
    __shared__ float4 gm4[12][2];      // [gate][row-bit]{ar,ai,br,bi}
    __shared__ float Ur[16][17];
    __shared__ float Ui[16][17];
    __shared__ float Amat[4][16][16];
    __shared__ float4 C4s[100];        // C[P*10+Q][w]
    __shared__ float q_lds[4][IPB][196];
    __shared__ float red[IPB][10];

    const int tid  = threadIdx.x;
    const int img0 = blockIdx.x * IPB;

    // ---- x load + patch trigonometry (hoisted: hides under prep barriers) ----
    const int iml   = (tid >= 196) ? 1 : 0;
    const int p_raw = tid - iml * 196;
    const int pidx  = (tid < 392) ? p_raw : 0;
    const int pi = pidx / 14, pj = pidx % 14;
    float T[10], U[10];
    {
        const int img = min(img0 + iml, B - 1);
        const float* xb = x + img * 784 + pi * 56 + pj * 2;
        const float2 r0 = *(const float2*)(xb);
        const float2 r1 = *(const float2*)(xb + 28);
        const float h0 = 0.5f * r0.x, h1 = 0.5f * r0.y;
        const float h2 = 0.5f * r1.x, h3 = 0.5f * r1.y;
        const float s0 = __sinf(h0), c0 = __cosf(h0);
        const float s1 = __sinf(h1), c1 = __cosf(h1);
        const float s2 = __sinf(h2), c2 = __cosf(h2);
        const float s3 = __sinf(h3), c3 = __cosf(h3);
        float t[4], u[4];
        t[0] = c0 * c1; t[1] = c0 * s1; t[2] = s0 * c1; t[3] = s0 * s1;
        u[0] = c2 * c3; u[1] = c2 * s3; u[2] = s2 * c3; u[3] = s2 * s3;
        int P = 0;
#pragma unroll
        for (int a = 0; a < 4; ++a)
#pragma unroll
            for (int b2 = a; b2 < 4; ++b2) {
                T[P] = t[a] * t[b2];
                U[P] = u[a] * u[b2];
                ++P;
            }
    }

    // ---- Phase AB: 12 lanes build gate matrices ----
    if (tid < 12) {
        const float phi = params[tid * 3 + 0];
        const float th  = params[tid * 3 + 1];
        const float om  = params[tid * 3 + 2];
        const float aa = 0.5f * (phi + om), ab = 0.5f * (phi - om), at = 0.5f * th;
        const float sa = __sinf(aa), ca = __cosf(aa);
        const float sb = __sinf(ab), cb = __cosf(ab);
        const float st = __sinf(at), ct = __cosf(at);
        gm4[tid][0] = make_float4( ct * ca, -ct * sa, -st * cb, -st * sb);
        gm4[tid][1] = make_float4( ct * ca,  ct * sa,  st * cb, -st * sb);
    }
    __syncthreads();

    // ---- Phase C: build U via shfl butterflies, threads 0..255 = (col,row) ----
    if (tid < 256) {
        const int col = tid >> 4, row = tid & 15;
        float sr = (row == col) ? 1.f : 0.f;
        float si = 0.f;
#pragma unroll
        for (int l = 0; l < 3; ++l) {
#pragma unroll
            for (int w = 0; w < 4; ++w) {
                const int g = l * 4 + w;
                const int m = 8 >> w;          // wire 0 = MSB
                const int bit = (row & m) ? 1 : 0;
                const float4 mm = gm4[g][bit];
                const float pr  = __shfl_xor(sr, m, 64);
                const float pi2 = __shfl_xor(si, m, 64);
                const float nsr = mm.x * sr - mm.y * si + mm.z * pr - mm.w * pi2;
                const float nsi = mm.x * si + mm.y * sr + mm.z * pi2 + mm.w * pr;
                sr = nsr; si = nsi;
            }
            const int r = (l % 3) + 1;
#pragma unroll
            for (int w = 0; w < 4; ++w) {
                const int cm = 8 >> w;
                const int tm = 8 >> ((w + r) & 3);
                const float pr  = __shfl_xor(sr, tm, 64);
                const float pi2 = __shfl_xor(si, tm, 64);
                const bool take = (row & cm) != 0;
                sr = take ? pr : sr;
                si = take ? pi2 : si;
            }
        }
        Ur[row][col] = sr;
        Ui[row][col] = si;
    }
    __syncthreads();

    // ---- Phase D: A[w][i][j] (threads 0..255 = (i,j)) ----
    if (tid < 256) {
        const int i = tid >> 4, j = tid & 15;
        float a0 = 0.f, a1 = 0.f, a2 = 0.f, a3 = 0.f;
#pragma unroll
        for (int k = 0; k < 16; ++k) {
            const float pr = Ur[k][i] * Ur[k][j] + Ui[k][i] * Ui[k][j];
            if (k & 8) a0 -= pr; else a0 += pr;
            if (k & 4) a1 -= pr; else a1 += pr;
            if (k & 2) a2 -= pr; else a2 += pr;
            if (k & 1) a3 -= pr; else a3 += pr;
        }
        Amat[0][i][j] = a0; Amat[1][i][j] = a1;
        Amat[2][i][j] = a2; Amat[3][i][j] = a3;
    }
    __syncthreads();

    // ---- Phase E: C tensor into LDS (400 items, one per thread) ----
    if (tid < 400) {
        const int w = tid & 3, pq = tid >> 2;
        const int P = pq / 10, Q = pq % 10;
        const int a = (P < 4) ? 0 : (P < 7) ? 1 : (P < 9) ? 2 : 3;
        const int b = (P < 4) ? P : (P < 7) ? P - 3 : (P < 9) ? P - 5 : 3;
        const int c = (Q < 4) ? 0 : (Q < 7) ? 1 : (Q < 9) ? 2 : 3;
        const int d = (Q < 4) ? Q : (Q < 7) ? Q - 3 : (Q < 9) ? Q - 5 : 3;
        const float s = 0.5f * (float)(1 << ((a != b) + (c != d)));
        const float val = s * (Amat[w][4 * a + c][4 * b + d] +
                               Amat[w][4 * a + d][4 * b + c]);
        ((float*)&C4s[pq])[w] = val;
    }
    __syncthreads();

    // ---- Patch phase: threads 0..391 (T/U already in registers) ----
    if (tid < 392) {
        float2 q01 = make_float2(0.f, 0.f), q23 = make_float2(0.f, 0.f);
#pragma unroll
        for (int P = 0; P < 10; ++P) {
            float2 s01 = make_float2(0.f, 0.f), s23 = make_float2(0.f, 0.f);
#pragma unroll
            for (int Q = 0; Q < 10; ++Q) {
                const float4 cc = C4s[P * 10 + Q];  // wave-uniform broadcast
                s01 = pkfma(make_float2(cc.x, cc.y), U[Q], s01);
                s23 = pkfma(make_float2(cc.z, cc.w), U[Q], s23);
            }
            q01 = pkfma(s01, T[P], q01);
            q23 = pkfma(s23, T[P], q23);
        }
        q_lds[0][iml][p_raw] = q01.x;
        q_lds[1][iml][p_raw] = q01.y;
        q_lds[2][iml][p_raw] = q23.x;
        q_lds[3][iml][p_raw] = q23.y;
    }
    __syncthreads();

    // ---- Logits: 320 threads = (img, o, c), c in [0,16) ----
    if (tid < 320) {
        const int img = tid / 160, rem = tid % 160;
        const int o = rem >> 4, c = rem & 15;
        const float4* Wp = (const float4*)Wm;
        float acc = 0.f;
#pragma unroll
        for (int k = 0; k < 13; ++k) {
            const int p = c + 16 * k;
            if (p < 196) {
                const float4 wv = Wp[o * 196 + p];
                acc = fmaf(wv.x, q_lds[0][img][p],
                      fmaf(wv.y, q_lds[1][img][p],
                      fmaf(wv.z, q_lds[2][img][p],
                      fmaf(wv.w, q_lds[3][img][p], acc))));
            }
        }
        acc += __shfl_down(acc, 1, 16);
        acc += __shfl_down(acc, 2, 16);
        acc += __shfl_down(acc, 4, 16);
        acc += __shfl_down(acc, 8, 16);
        if (c == 0) red[img][o] = acc + bv[o];
    }
    __syncthreads();

    // ---- Final: per-image log_softmax ----
    if (tid < IPB) {
        const int img = img0 + tid;
        if (img < B) {
            float lo[10];
            float mx = -1e30f;
#pragma unroll
            for (int o = 0; o < 10; ++o) { lo[o] = red[tid][o]; mx = fmaxf(mx, lo[o]); }
            float se = 0.f;
#pragma unroll
            for (int o = 0; o < 10; ++o) se += __expf(lo[o] - mx);
            const float lse = mx + __logf(se);
#pragma unroll
            for (int o = 0; o < 10; ++o) out[img * 10 + o] = lo[o] - lse;
        }
    }
}

extern "C" void kernel_launch(void* const* d_in, const int* in_sizes, int n_in,
                              void* d_out, int out_size, void* d_ws, size_t ws_size,
                              hipStream_t stream) {
    const float* x      = (const float*)d_in[0];  // [B,1,28,28]
    const float* params = (const float*)d_in[1];  // [3,4,3]
    const float* Wm     = (const float*)d_in[2];  // [10,784]
    const float* bv     = (const float*)d_in[3];  // [10]
    float* out          = (float*)d_out;          // [B,10]

    const int B = in_sizes[0] / 784;
    const int nblk = (B + IPB - 1) / IPB;
    quanv_fused5_kernel<<<nblk, BLK, 0, stream>>>(x, params, Wm, bv, out, B);
}